// Round 15
// baseline (307.288 us; speedup 1.0000x reference)
//
#include <hip/hip_runtime.h>
#include <hip/hip_bf16.h>
#include <math.h>

// Problem constants (from reference setup_inputs)
#define BB 32
#define NN 1024
#define DD 64
#define TT 2048
#define CHUNKS (TT / 256)   // 8 column-chunks of 256
#define SEGS 16             // n-segments (decoupled scan)

typedef float f32x4 __attribute__((ext_vector_type(4)));

// alpha in LOG2 units: exp() becomes bare v_exp_f32. Validated R9/R10/R12.
#define NLOG2E_HALF (-0.72134752044448169f)   // -0.5 * log2(e)

__device__ __forceinline__ float exp2_fast(float x) {
    return __builtin_amdgcn_exp2f(x);
}

// DPP move WITHOUT tied-old operand -> fuses into the consumer op.
template<int CTRL>
__device__ __forceinline__ float dpp_mov_f(float v) {
    return __int_as_float(
        __builtin_amdgcn_mov_dpp(__float_as_int(v), CTRL, 0xF, 0xF, true));
}

// All-lanes butterfly reduce over groups of 2^GB lanes.
template<int GB>
__device__ __forceinline__ float groupMax(float v) {
    v = fmaxf(v, dpp_mov_f<0x0B1>(v));  // xor1
    v = fmaxf(v, dpp_mov_f<0x04E>(v));  // xor2
    v = fmaxf(v, dpp_mov_f<0x141>(v));  // xor4 (row_half_mirror)
    v = fmaxf(v, dpp_mov_f<0x140>(v));  // xor8 (row_mirror)
    if constexpr (GB == 6) {
        v = fmaxf(v, __shfl_xor(v, 16));
        v = fmaxf(v, __shfl_xor(v, 32));
    }
    return v;
}

template<int GB>
__device__ __forceinline__ float groupSum(float v) {
    v += dpp_mov_f<0x0B1>(v);
    v += dpp_mov_f<0x04E>(v);
    v += dpp_mov_f<0x141>(v);
    v += dpp_mov_f<0x140>(v);
    if constexpr (GB == 6) {
        v += __shfl_xor(v, 16);
        v += __shfl_xor(v, 32);
    }
    return v;
}

__device__ __forceinline__ void loadW(const float* __restrict__ W, int col,
                                      f32x4* wv) {
#pragma unroll
    for (int i = 0; i < 16; ++i) {
        wv[i].x = W[(size_t)(4 * i + 0) * TT + col];
        wv[i].y = W[(size_t)(4 * i + 1) * TT + col];
        wv[i].z = W[(size_t)(4 * i + 2) * TT + col];
        wv[i].w = W[(size_t)(4 * i + 3) * TT + col];
    }
}

__device__ __forceinline__ float hsum(f32x4 s) {
    return (s.x + s.y) + (s.z + s.w);
}

// 4 independent dots vs the same W column (plain loop, compiler-scheduled).
__device__ __forceinline__ void dot4(const float* __restrict__ x0p,
                                     const f32x4* wv, float* xw) {
    const f32x4* xr0 = (const f32x4*)(x0p);
    const f32x4* xr1 = (const f32x4*)(x0p + DD);
    const f32x4* xr2 = (const f32x4*)(x0p + 2 * DD);
    const f32x4* xr3 = (const f32x4*)(x0p + 3 * DD);
    f32x4 s0 = {0.f, 0.f, 0.f, 0.f};
    f32x4 s1 = {0.f, 0.f, 0.f, 0.f};
    f32x4 s2 = {0.f, 0.f, 0.f, 0.f};
    f32x4 s3 = {0.f, 0.f, 0.f, 0.f};
#pragma unroll
    for (int i = 0; i < 16; ++i) {
        const f32x4 w = wv[i];
        s0 += xr0[i] * w;
        s1 += xr1[i] * w;
        s2 += xr2[i] * w;
        s3 += xr3[i] * w;
    }
    xw[0] = hsum(s0); xw[1] = hsum(s1); xw[2] = hsum(s2); xw[3] = hsum(s3);
}

// Pass A: per-(b, t, segment) sum of log-probs (log2 units). At its issue
// floor (~65 us, R5) — unchanged.
template<int SEG>
__global__ __launch_bounds__(256, 4)
void segsum_kernel(const float* __restrict__ data,
                   const float* __restrict__ targets,
                   const float* __restrict__ W,
                   float* __restrict__ segsum)
{
    constexpr int NSEG = NN / SEG;
    const int blk   = blockIdx.x;
    const int s     = blk % SEG;
    const int rem   = blk / SEG;
    const int chunk = rem % CHUNKS;
    const int b     = rem / CHUNKS;
    const int tid   = threadIdx.x;
    const int col   = chunk * 256 + tid;

    f32x4 wv[16];
    loadW(W, col, wv);

    const float* xb = data + (size_t)b * NN * DD;
    const float* tb = targets + (size_t)b * NN;

    const int n0 = s * NSEG;
    float acc = 0.0f;
    for (int n = n0; n < n0 + NSEG; n += 4) {
        float xw[4];
        dot4(xb + (size_t)n * DD, wv, xw);
#pragma unroll
        for (int j = 0; j < 4; ++j) {
            const float d = tb[n + j] - xw[j];
            acc = fmaf(d * d, NLOG2E_HALF, acc);
        }
    }
    segsum[((size_t)b * SEG + s) * TT + col] = acc;
}

// Pass B: quad-stream scan with LDS-staged x (compiler-managed waits ONLY).
// Per wave, per stream: double-buffered 1 KB quad in LDS. Loop body:
//   (1) issue coalesced per-lane 16B global loads of quad q+1 (4 VGPRs/stream)
//   (2) compute quad q from LDS via uniform ds_read (broadcast, no conflict)
//   (3) ds_write quad q+1 (compiler's auto vmcnt wait lands AFTER the whole
//       compute phase -> HBM/L2 latency hidden; LDS ops are in-order per
//       wave so the next iteration's reads are safe with no barriers)
// This removes the per-quad SGPR-window serialization (s_load -> wait ->
// consume) that pinned VALUBusy at 61% regardless of stream count (R12=R14).
// Float values identical to R14 -> bitwise-equal partials.
template<int SEG, int GB>
__global__ __launch_bounds__(256)
void scan4_kernel(const float* __restrict__ data,
                  const float* __restrict__ targets,
                  const float* __restrict__ W,
                  const float* __restrict__ segsum,
                  float* __restrict__ mP,
                  float* __restrict__ sP,
                  float* __restrict__ pP)
{
    constexpr int NSEG  = NN / SEG;
    constexpr int QUADS = NSEG / 4;
    constexpr int QTR   = SEG / 4;            // 4 stream-base slots
    constexpr int PPN   = TT >> GB;           // partials per (b,n)

    __shared__ __align__(16) float xs[4][4][2][4 * DD];  // [wave][stream][buf] = 32 KB

    const int blk   = blockIdx.x;
    const int sA    = blk % QTR;              // base segment (0..3)
    const int rem   = blk / QTR;
    const int chunk = rem % CHUNKS;
    const int b     = rem / CHUNKS;
    const int tid   = threadIdx.x;
    const int wave  = tid >> 6;
    const int lane  = tid & 63;
    const int col   = chunk * 256 + tid;

    const int s0 = sA, s1 = sA + QTR, s2 = sA + 2 * QTR, s3 = sA + 3 * QTR;

    f32x4 wv[16];
    loadW(W, col, wv);

    const float* xb = data + (size_t)b * NN * DD;
    const float* tb = targets + (size_t)b * NN;

    const int  k      = (chunk * 256 + (tid & ~((1 << GB) - 1))) >> GB;
    const bool writer = (lane & ((1 << GB) - 1)) == 0;
    const size_t base0 = (size_t)b * NN * PPN + k;

    // exclusive segment prefixes for the 4 streams (log2 units)
    float alpha0 = 0.0f, alpha1 = 0.0f, alpha2 = 0.0f, alpha3 = 0.0f;
    for (int s2i = 0; s2i < SEG - 1; ++s2i) {
        const float v = segsum[((size_t)b * SEG + s2i) * TT + col];
        if (s2i < s0) alpha0 += v;
        if (s2i < s1) alpha1 += v;
        if (s2i < s2) alpha2 += v;
        if (s2i < s3) alpha3 += v;
    }

    const int n00 = s0 * NSEG, n01 = s1 * NSEG, n02 = s2 * NSEG, n03 = s3 * NSEG;

    // full softmax+emit for one quad of one stream (x from LDS buffer).
    auto quad = [&](float& alpha, int n, const float* xbuf) {
        float xw[4];
        dot4(xbuf, wv, xw);
        float a[4];
        float al = alpha;
#pragma unroll
        for (int j = 0; j < 4; ++j) {
            a[j] = al;
            const float d = tb[n + j] - xw[j];
            al = fmaf(d * d, NLOG2E_HALF, al);
        }
        alpha = al;
        float m[4], e[4], qv[4], sv[4], pv[4];
#pragma unroll
        for (int j = 0; j < 4; ++j) m[j] = groupMax<GB>(a[j]);
#pragma unroll
        for (int j = 0; j < 4; ++j) {
            e[j]  = exp2_fast(a[j] - m[j]);
            qv[j] = e[j] * xw[j];
        }
#pragma unroll
        for (int j = 0; j < 4; ++j) sv[j] = groupSum<GB>(e[j]);
#pragma unroll
        for (int j = 0; j < 4; ++j) pv[j] = groupSum<GB>(qv[j]);
        if (writer) {
            const size_t i0 = base0 + (size_t)n * PPN;
#pragma unroll
            for (int j = 0; j < 4; ++j) {
                mP[i0 + (size_t)j * PPN] = m[j];
                sP[i0 + (size_t)j * PPN] = sv[j];
                pP[i0 + (size_t)j * PPN] = pv[j];
            }
        }
    };

    // prologue: stage quad 0 of each stream into buf 0 (load -> LDS).
    {
        const f32x4 r0 = *(const f32x4*)(xb + (size_t)n00 * DD + 4 * lane);
        const f32x4 r1 = *(const f32x4*)(xb + (size_t)n01 * DD + 4 * lane);
        const f32x4 r2 = *(const f32x4*)(xb + (size_t)n02 * DD + 4 * lane);
        const f32x4 r3 = *(const f32x4*)(xb + (size_t)n03 * DD + 4 * lane);
        *(f32x4*)&xs[wave][0][0][4 * lane] = r0;
        *(f32x4*)&xs[wave][1][0][4 * lane] = r1;
        *(f32x4*)&xs[wave][2][0][4 * lane] = r2;
        *(f32x4*)&xs[wave][3][0][4 * lane] = r3;
    }

#pragma unroll 1
    for (int q = 0; q < QUADS; ++q) {
        const int buf = q & 1;
        const int nq  = 4 * q;
        const int nn  = (q + 1 < QUADS) ? nq + 4 : nq;   // last iter: dummy (in-bounds)

        // (1) issue next-quad loads (coalesced 16B/lane; latency hidden
        //     under the compute phase below — compiler sinks the dependent
        //     ds_write, not the loads)
        const f32x4 p0 = *(const f32x4*)(xb + (size_t)(n00 + nn) * DD + 4 * lane);
        const f32x4 p1 = *(const f32x4*)(xb + (size_t)(n01 + nn) * DD + 4 * lane);
        const f32x4 p2 = *(const f32x4*)(xb + (size_t)(n02 + nn) * DD + 4 * lane);
        const f32x4 p3 = *(const f32x4*)(xb + (size_t)(n03 + nn) * DD + 4 * lane);

        // (2) compute current quads from LDS (uniform ds_read broadcasts)
        quad(alpha0, n00 + nq, &xs[wave][0][buf][0]);
        quad(alpha1, n01 + nq, &xs[wave][1][buf][0]);
        quad(alpha2, n02 + nq, &xs[wave][2][buf][0]);
        quad(alpha3, n03 + nq, &xs[wave][3][buf][0]);

        // (3) write next-quad data into the alternate buffers
        *(f32x4*)&xs[wave][0][buf ^ 1][4 * lane] = p0;
        *(f32x4*)&xs[wave][1][buf ^ 1][4 * lane] = p1;
        *(f32x4*)&xs[wave][2][buf ^ 1][4 * lane] = p2;
        *(f32x4*)&xs[wave][3][buf ^ 1][4 * lane] = p3;
    }
}

// Single-stream scan (fallback path only).
template<int SEG, int GB>
__global__ __launch_bounds__(256, 4)
void scan_kernel(const float* __restrict__ data,
                 const float* __restrict__ targets,
                 const float* __restrict__ W,
                 const float* __restrict__ segsum,
                 float* __restrict__ mP,
                 float* __restrict__ sP,
                 float* __restrict__ pP)
{
    constexpr int NSEG = NN / SEG;
    constexpr int PPN  = TT >> GB;
    const int blk   = blockIdx.x;
    const int s     = blk % SEG;
    const int rem   = blk / SEG;
    const int chunk = rem % CHUNKS;
    const int b     = rem / CHUNKS;
    const int tid   = threadIdx.x;
    const int lane  = tid & 63;
    const int col   = chunk * 256 + tid;

    f32x4 wv[16];
    loadW(W, col, wv);

    const float* xb = data + (size_t)b * NN * DD;
    const float* tb = targets + (size_t)b * NN;

    const int  k      = (chunk * 256 + (tid & ~((1 << GB) - 1))) >> GB;
    const bool writer = (lane & ((1 << GB) - 1)) == 0;
    const size_t base0 = (size_t)b * NN * PPN + k;

    float alpha = 0.0f;
    if constexpr (SEG > 1) {
        for (int s2 = 0; s2 < s; ++s2)
            alpha += segsum[((size_t)b * SEG + s2) * TT + col];
    }

    const int n0 = s * NSEG;
    for (int n = n0; n < n0 + NSEG; n += 4) {
        float xw[4];
        dot4(xb + (size_t)n * DD, wv, xw);
        float a[4];
        float al = alpha;
#pragma unroll
        for (int j = 0; j < 4; ++j) {
            a[j] = al;
            const float d = tb[n + j] - xw[j];
            al = fmaf(d * d, NLOG2E_HALF, al);
        }
        alpha = al;
        float m[4], e[4], qv[4], sv[4], pv[4];
#pragma unroll
        for (int j = 0; j < 4; ++j) m[j] = groupMax<GB>(a[j]);
#pragma unroll
        for (int j = 0; j < 4; ++j) {
            e[j]  = exp2_fast(a[j] - m[j]);
            qv[j] = e[j] * xw[j];
        }
#pragma unroll
        for (int j = 0; j < 4; ++j) sv[j] = groupSum<GB>(e[j]);
#pragma unroll
        for (int j = 0; j < 4; ++j) pv[j] = groupSum<GB>(qv[j]);
        if (writer) {
            const size_t i0 = base0 + (size_t)n * PPN;
#pragma unroll
            for (int j = 0; j < 4; ++j) {
                mP[i0 + (size_t)j * PPN] = m[j];
                sP[i0 + (size_t)j * PPN] = sv[j];
                pP[i0 + (size_t)j * PPN] = pv[j];
            }
        }
    }
}

// Pass C: one wave per (b,n): merge PPN partials (log2 units).
template<int PPN>
__global__ __launch_bounds__(256)
void combine_kernel(const float* __restrict__ mP,
                    const float* __restrict__ sP,
                    const float* __restrict__ pP,
                    float* __restrict__ out)
{
    const int wgid = blockIdx.x * 4 + (threadIdx.x >> 6);   // = b*NN + n
    const int lane = threadIdx.x & 63;
    const size_t base = (size_t)wgid * PPN;

    float m = -INFINITY, s = 0.0f, p = 0.0f;
    if constexpr (PPN >= 64) {
#pragma unroll
        for (int j = 0; j < PPN / 64; ++j) {
            const size_t idx = base + lane + j * 64;
            const float mk = mP[idx], sk = sP[idx], pk = pP[idx];
            const float M  = fmaxf(m, mk);
            const float e1 = exp2_fast(m - M), e2 = exp2_fast(mk - M);
            s = s * e1 + sk * e2;
            p = p * e1 + pk * e2;
            m = M;
        }
    } else {
        if (lane < PPN) {
            m = mP[base + lane]; s = sP[base + lane]; p = pP[base + lane];
        }
    }

#pragma unroll
    for (int off = 1; off < 64; off <<= 1) {
        const float mo = __shfl_xor(m, off);
        const float so = __shfl_xor(s, off);
        const float po = __shfl_xor(p, off);
        const float M  = fmaxf(m, mo);
        const float e1 = exp2_fast(m - M), e2 = exp2_fast(mo - M);
        s = s * e1 + so * e2;
        p = p * e1 + po * e2;
        m = M;
    }

    if (lane == 0) out[wgid] = p / s;
}

extern "C" void kernel_launch(void* const* d_in, const int* in_sizes, int n_in,
                              void* d_out, int out_size, void* d_ws, size_t ws_size,
                              hipStream_t stream)
{
    (void)in_sizes; (void)n_in; (void)out_size;
    const float* data    = (const float*)d_in[0];
    const float* targets = (const float*)d_in[1];
    const float* W       = (const float*)d_in[2];
    float* out = (float*)d_out;

    const size_t plane4 = (size_t)BB * NN * (TT >> 4);   // GB=4: 128 partials/(b,n)
    const size_t plane6 = (size_t)BB * NN * (TT >> 6);   // GB=6: 32 partials/(b,n)
    const size_t seg16  = (size_t)BB * SEGS * TT;

    const int scan4_grid = BB * CHUNKS * (SEGS / 4);     // 1024 blocks of 256

    if (ws_size >= (3 * plane4 + seg16) * sizeof(float)) {
        // ~54 MB path: SEG=16, GB=4, quad-stream scan + LDS x-staging
        float* mP = (float*)d_ws;
        float* sP = mP + plane4;
        float* pP = sP + plane4;
        float* sg = pP + plane4;
        segsum_kernel<SEGS><<<BB * CHUNKS * SEGS, 256, 0, stream>>>(data, targets, W, sg);
        scan4_kernel<SEGS, 4><<<scan4_grid, 256, 0, stream>>>(data, targets, W, sg, mP, sP, pP);
        combine_kernel<128><<<(BB * NN) / 4, 256, 0, stream>>>(mP, sP, pP, out);
    } else if (ws_size >= (3 * plane6 + seg16) * sizeof(float)) {
        // ~17 MB path: SEG=16, GB=6, quad-stream scan + LDS x-staging
        float* mP = (float*)d_ws;
        float* sP = mP + plane6;
        float* pP = sP + plane6;
        float* sg = pP + plane6;
        segsum_kernel<SEGS><<<BB * CHUNKS * SEGS, 256, 0, stream>>>(data, targets, W, sg);
        scan4_kernel<SEGS, 6><<<scan4_grid, 256, 0, stream>>>(data, targets, W, sg, mP, sP, pP);
        combine_kernel<32><<<(BB * NN) / 4, 256, 0, stream>>>(mP, sP, pP, out);
    } else {
        // 12 MB fallback: no segmentation (slow but correct)
        float* mP = (float*)d_ws;
        float* sP = mP + plane6;
        float* pP = sP + plane6;
        scan_kernel<1, 6><<<BB * CHUNKS, 256, 0, stream>>>(data, targets, W, nullptr, mP, sP, pP);
        combine_kernel<32><<<(BB * NN) / 4, 256, 0, stream>>>(mP, sP, pP, out);
    }
}

// Round 16
// 304.512 us; speedup vs baseline: 1.0091x; 1.0091x over previous
//
#include <hip/hip_runtime.h>
#include <hip/hip_bf16.h>
#include <math.h>

// Problem constants (from reference setup_inputs)
#define BB 32
#define NN 1024
#define DD 64
#define TT 2048
#define CHUNKS (TT / 256)   // 8 column-chunks of 256
#define SEGS 16             // n-segments (decoupled scan)

typedef float f32x2 __attribute__((ext_vector_type(2)));

// alpha in LOG2 units: exp() becomes bare v_exp_f32. Validated R9/R10/R12.
#define NLOG2E_HALF (-0.72134752044448169f)   // -0.5 * log2(e)

__device__ __forceinline__ float exp2_fast(float x) {
    return __builtin_amdgcn_exp2f(x);
}

// DPP move WITHOUT tied-old operand -> fuses into the consumer op.
template<int CTRL>
__device__ __forceinline__ float dpp_mov_f(float v) {
    return __int_as_float(
        __builtin_amdgcn_mov_dpp(__float_as_int(v), CTRL, 0xF, 0xF, true));
}

// All-lanes butterfly reduce over groups of 2^GB lanes.
template<int GB>
__device__ __forceinline__ float groupMax(float v) {
    v = fmaxf(v, dpp_mov_f<0x0B1>(v));  // xor1
    v = fmaxf(v, dpp_mov_f<0x04E>(v));  // xor2
    v = fmaxf(v, dpp_mov_f<0x141>(v));  // xor4 (row_half_mirror)
    v = fmaxf(v, dpp_mov_f<0x140>(v));  // xor8 (row_mirror)
    if constexpr (GB == 6) {
        v = fmaxf(v, __shfl_xor(v, 16));
        v = fmaxf(v, __shfl_xor(v, 32));
    }
    return v;
}

template<int GB>
__device__ __forceinline__ float groupSum(float v) {
    v += dpp_mov_f<0x0B1>(v);
    v += dpp_mov_f<0x04E>(v);
    v += dpp_mov_f<0x141>(v);
    v += dpp_mov_f<0x140>(v);
    if constexpr (GB == 6) {
        v += __shfl_xor(v, 16);
        v += __shfl_xor(v, 32);
    }
    return v;
}

// W column as 32 f32x2 pairs: wv[j] = (W[2j][col], W[2j+1][col]).
__device__ __forceinline__ void loadW(const float* __restrict__ W, int col,
                                      f32x2* wv) {
#pragma unroll
    for (int j = 0; j < 32; ++j) {
        wv[j].x = W[(size_t)(2 * j + 0) * TT + col];
        wv[j].y = W[(size_t)(2 * j + 1) * TT + col];
    }
}

// 4 independent dots vs the same W column using PACKED fp32 FMA
// (llvm.fma.v2f32 -> v_pk_fma_f32: 2 MACs/inst, 2x the fp32 rate).
// Pair j covers elements (2j, 2j+1); even j -> accumulator A (d = 0,1 mod 4),
// odd j -> accumulator B (d = 2,3 mod 4). So A = (a0, a1), B = (a2, a3) and
// (A.x+A.y)+(B.x+B.y) is EXACTLY the original dot64 association ->
// bitwise-identical xw.
__device__ __forceinline__ void dot4(const float* __restrict__ x0p,
                                     const f32x2* wv, float* xw) {
    const f32x2* xr0 = (const f32x2*)(x0p);
    const f32x2* xr1 = (const f32x2*)(x0p + DD);
    const f32x2* xr2 = (const f32x2*)(x0p + 2 * DD);
    const f32x2* xr3 = (const f32x2*)(x0p + 3 * DD);
    f32x2 a0 = {0.f, 0.f}, b0 = {0.f, 0.f};
    f32x2 a1 = {0.f, 0.f}, b1 = {0.f, 0.f};
    f32x2 a2 = {0.f, 0.f}, b2 = {0.f, 0.f};
    f32x2 a3 = {0.f, 0.f}, b3 = {0.f, 0.f};
#pragma unroll
    for (int j = 0; j < 32; j += 2) {
        const f32x2 wA = wv[j], wB = wv[j + 1];
        a0 = __builtin_elementwise_fma(xr0[j],     wA, a0);
        b0 = __builtin_elementwise_fma(xr0[j + 1], wB, b0);
        a1 = __builtin_elementwise_fma(xr1[j],     wA, a1);
        b1 = __builtin_elementwise_fma(xr1[j + 1], wB, b1);
        a2 = __builtin_elementwise_fma(xr2[j],     wA, a2);
        b2 = __builtin_elementwise_fma(xr2[j + 1], wB, b2);
        a3 = __builtin_elementwise_fma(xr3[j],     wA, a3);
        b3 = __builtin_elementwise_fma(xr3[j + 1], wB, b3);
    }
    xw[0] = (a0.x + a0.y) + (b0.x + b0.y);
    xw[1] = (a1.x + a1.y) + (b1.x + b1.y);
    xw[2] = (a2.x + a2.y) + (b2.x + b2.y);
    xw[3] = (a3.x + a3.y) + (b3.x + b3.y);
}

// Pass A: per-(b, t, segment) sum of log-probs (log2 units).
template<int SEG>
__global__ __launch_bounds__(256, 4)
void segsum_kernel(const float* __restrict__ data,
                   const float* __restrict__ targets,
                   const float* __restrict__ W,
                   float* __restrict__ segsum)
{
    constexpr int NSEG = NN / SEG;
    const int blk   = blockIdx.x;
    const int s     = blk % SEG;
    const int rem   = blk / SEG;
    const int chunk = rem % CHUNKS;
    const int b     = rem / CHUNKS;
    const int tid   = threadIdx.x;
    const int col   = chunk * 256 + tid;

    f32x2 wv[32];
    loadW(W, col, wv);

    const float* xb = data + (size_t)b * NN * DD;
    const float* tb = targets + (size_t)b * NN;

    const int n0 = s * NSEG;
    float acc = 0.0f;
    for (int n = n0; n < n0 + NSEG; n += 4) {
        float xw[4];
        dot4(xb + (size_t)n * DD, wv, xw);
#pragma unroll
        for (int j = 0; j < 4; ++j) {
            const float d = tb[n + j] - xw[j];
            acc = fmaf(d * d, NLOG2E_HALF, acc);
        }
    }
    segsum[((size_t)b * SEG + s) * TT + col] = acc;
}

// Pass B: QUAD-stream scan (R14 structure — best measured: 200 us).
// All 4 waves of a block share segment set + 256 columns (scalar x loads,
// full-line partial writes); each wave runs 4 independent segment streams.
template<int SEG, int GB>
__global__ __launch_bounds__(256)
void scan4_kernel(const float* __restrict__ data,
                  const float* __restrict__ targets,
                  const float* __restrict__ W,
                  const float* __restrict__ segsum,
                  float* __restrict__ mP,
                  float* __restrict__ sP,
                  float* __restrict__ pP)
{
    constexpr int NSEG = NN / SEG;
    constexpr int QTR  = SEG / 4;             // 4 stream-base slots
    constexpr int PPN  = TT >> GB;            // partials per (b,n)
    const int blk   = blockIdx.x;
    const int sA    = blk % QTR;              // base segment (0..3)
    const int rem   = blk / QTR;
    const int chunk = rem % CHUNKS;
    const int b     = rem / CHUNKS;
    const int tid   = threadIdx.x;
    const int lane  = tid & 63;
    const int col   = chunk * 256 + tid;

    const int s0 = sA, s1 = sA + QTR, s2 = sA + 2 * QTR, s3 = sA + 3 * QTR;

    f32x2 wv[32];
    loadW(W, col, wv);

    const float* xb = data + (size_t)b * NN * DD;
    const float* tb = targets + (size_t)b * NN;

    const int  k      = (chunk * 256 + (tid & ~((1 << GB) - 1))) >> GB;
    const bool writer = (lane & ((1 << GB) - 1)) == 0;
    const size_t base0 = (size_t)b * NN * PPN + k;

    // exclusive segment prefixes for the 4 streams (log2 units)
    float alpha0 = 0.0f, alpha1 = 0.0f, alpha2 = 0.0f, alpha3 = 0.0f;
    for (int s2i = 0; s2i < SEG - 1; ++s2i) {
        const float v = segsum[((size_t)b * SEG + s2i) * TT + col];
        if (s2i < s0) alpha0 += v;
        if (s2i < s1) alpha1 += v;
        if (s2i < s2) alpha2 += v;
        if (s2i < s3) alpha3 += v;
    }

    // full softmax+emit for one quad of one stream; updates that alpha.
    auto quad = [&](float& alpha, int n) {
        float xw[4];
        dot4(xb + (size_t)n * DD, wv, xw);
        float a[4];
        float al = alpha;
#pragma unroll
        for (int j = 0; j < 4; ++j) {
            a[j] = al;
            const float d = tb[n + j] - xw[j];
            al = fmaf(d * d, NLOG2E_HALF, al);
        }
        alpha = al;
        float m[4], e[4], qv[4], sv[4], pv[4];
#pragma unroll
        for (int j = 0; j < 4; ++j) m[j] = groupMax<GB>(a[j]);
#pragma unroll
        for (int j = 0; j < 4; ++j) {
            e[j]  = exp2_fast(a[j] - m[j]);
            qv[j] = e[j] * xw[j];
        }
#pragma unroll
        for (int j = 0; j < 4; ++j) sv[j] = groupSum<GB>(e[j]);
#pragma unroll
        for (int j = 0; j < 4; ++j) pv[j] = groupSum<GB>(qv[j]);
        if (writer) {
            const size_t i0 = base0 + (size_t)n * PPN;
#pragma unroll
            for (int j = 0; j < 4; ++j) {
                mP[i0 + (size_t)j * PPN] = m[j];
                sP[i0 + (size_t)j * PPN] = sv[j];
                pP[i0 + (size_t)j * PPN] = pv[j];
            }
        }
    };

    const int n00 = s0 * NSEG;
    const int n01 = s1 * NSEG;
    const int n02 = s2 * NSEG;
    const int n03 = s3 * NSEG;
#pragma unroll 1
    for (int i = 0; i < NSEG; i += 4) {
        quad(alpha0, n00 + i);   // four independent streams: the compiler
        quad(alpha1, n01 + i);   // interleaves them to fill dep stalls
        quad(alpha2, n02 + i);
        quad(alpha3, n03 + i);
    }
}

// Single-stream scan (fallback path only).
template<int SEG, int GB>
__global__ __launch_bounds__(256, 4)
void scan_kernel(const float* __restrict__ data,
                 const float* __restrict__ targets,
                 const float* __restrict__ W,
                 const float* __restrict__ segsum,
                 float* __restrict__ mP,
                 float* __restrict__ sP,
                 float* __restrict__ pP)
{
    constexpr int NSEG = NN / SEG;
    constexpr int PPN  = TT >> GB;
    const int blk   = blockIdx.x;
    const int s     = blk % SEG;
    const int rem   = blk / SEG;
    const int chunk = rem % CHUNKS;
    const int b     = rem / CHUNKS;
    const int tid   = threadIdx.x;
    const int lane  = tid & 63;
    const int col   = chunk * 256 + tid;

    f32x2 wv[32];
    loadW(W, col, wv);

    const float* xb = data + (size_t)b * NN * DD;
    const float* tb = targets + (size_t)b * NN;

    const int  k      = (chunk * 256 + (tid & ~((1 << GB) - 1))) >> GB;
    const bool writer = (lane & ((1 << GB) - 1)) == 0;
    const size_t base0 = (size_t)b * NN * PPN + k;

    float alpha = 0.0f;
    if constexpr (SEG > 1) {
        for (int s2 = 0; s2 < s; ++s2)
            alpha += segsum[((size_t)b * SEG + s2) * TT + col];
    }

    const int n0 = s * NSEG;
    for (int n = n0; n < n0 + NSEG; n += 4) {
        float xw[4];
        dot4(xb + (size_t)n * DD, wv, xw);
        float a[4];
        float al = alpha;
#pragma unroll
        for (int j = 0; j < 4; ++j) {
            a[j] = al;
            const float d = tb[n + j] - xw[j];
            al = fmaf(d * d, NLOG2E_HALF, al);
        }
        alpha = al;
        float m[4], e[4], qv[4], sv[4], pv[4];
#pragma unroll
        for (int j = 0; j < 4; ++j) m[j] = groupMax<GB>(a[j]);
#pragma unroll
        for (int j = 0; j < 4; ++j) {
            e[j]  = exp2_fast(a[j] - m[j]);
            qv[j] = e[j] * xw[j];
        }
#pragma unroll
        for (int j = 0; j < 4; ++j) sv[j] = groupSum<GB>(e[j]);
#pragma unroll
        for (int j = 0; j < 4; ++j) pv[j] = groupSum<GB>(qv[j]);
        if (writer) {
            const size_t i0 = base0 + (size_t)n * PPN;
#pragma unroll
            for (int j = 0; j < 4; ++j) {
                mP[i0 + (size_t)j * PPN] = m[j];
                sP[i0 + (size_t)j * PPN] = sv[j];
                pP[i0 + (size_t)j * PPN] = pv[j];
            }
        }
    }
}

// Pass C: one wave per (b,n): merge PPN partials (log2 units).
template<int PPN>
__global__ __launch_bounds__(256)
void combine_kernel(const float* __restrict__ mP,
                    const float* __restrict__ sP,
                    const float* __restrict__ pP,
                    float* __restrict__ out)
{
    const int wgid = blockIdx.x * 4 + (threadIdx.x >> 6);   // = b*NN + n
    const int lane = threadIdx.x & 63;
    const size_t base = (size_t)wgid * PPN;

    float m = -INFINITY, s = 0.0f, p = 0.0f;
    if constexpr (PPN >= 64) {
#pragma unroll
        for (int j = 0; j < PPN / 64; ++j) {
            const size_t idx = base + lane + j * 64;
            const float mk = mP[idx], sk = sP[idx], pk = pP[idx];
            const float M  = fmaxf(m, mk);
            const float e1 = exp2_fast(m - M), e2 = exp2_fast(mk - M);
            s = s * e1 + sk * e2;
            p = p * e1 + pk * e2;
            m = M;
        }
    } else {
        if (lane < PPN) {
            m = mP[base + lane]; s = sP[base + lane]; p = pP[base + lane];
        }
    }

#pragma unroll
    for (int off = 1; off < 64; off <<= 1) {
        const float mo = __shfl_xor(m, off);
        const float so = __shfl_xor(s, off);
        const float po = __shfl_xor(p, off);
        const float M  = fmaxf(m, mo);
        const float e1 = exp2_fast(m - M), e2 = exp2_fast(mo - M);
        s = s * e1 + so * e2;
        p = p * e1 + po * e2;
        m = M;
    }

    if (lane == 0) out[wgid] = p / s;
}

extern "C" void kernel_launch(void* const* d_in, const int* in_sizes, int n_in,
                              void* d_out, int out_size, void* d_ws, size_t ws_size,
                              hipStream_t stream)
{
    (void)in_sizes; (void)n_in; (void)out_size;
    const float* data    = (const float*)d_in[0];
    const float* targets = (const float*)d_in[1];
    const float* W       = (const float*)d_in[2];
    float* out = (float*)d_out;

    const size_t plane4 = (size_t)BB * NN * (TT >> 4);   // GB=4: 128 partials/(b,n)
    const size_t plane6 = (size_t)BB * NN * (TT >> 6);   // GB=6: 32 partials/(b,n)
    const size_t seg16  = (size_t)BB * SEGS * TT;

    const int scan4_grid = BB * CHUNKS * (SEGS / 4);     // 1024 blocks of 256

    if (ws_size >= (3 * plane4 + seg16) * sizeof(float)) {
        // ~54 MB path: SEG=16, GB=4, quad-stream scan, packed-fp32 dot
        float* mP = (float*)d_ws;
        float* sP = mP + plane4;
        float* pP = sP + plane4;
        float* sg = pP + plane4;
        segsum_kernel<SEGS><<<BB * CHUNKS * SEGS, 256, 0, stream>>>(data, targets, W, sg);
        scan4_kernel<SEGS, 4><<<scan4_grid, 256, 0, stream>>>(data, targets, W, sg, mP, sP, pP);
        combine_kernel<128><<<(BB * NN) / 4, 256, 0, stream>>>(mP, sP, pP, out);
    } else if (ws_size >= (3 * plane6 + seg16) * sizeof(float)) {
        // ~17 MB path: SEG=16, GB=6
        float* mP = (float*)d_ws;
        float* sP = mP + plane6;
        float* pP = sP + plane6;
        float* sg = pP + plane6;
        segsum_kernel<SEGS><<<BB * CHUNKS * SEGS, 256, 0, stream>>>(data, targets, W, sg);
        scan4_kernel<SEGS, 6><<<scan4_grid, 256, 0, stream>>>(data, targets, W, sg, mP, sP, pP);
        combine_kernel<32><<<(BB * NN) / 4, 256, 0, stream>>>(mP, sP, pP, out);
    } else {
        // 12 MB fallback: no segmentation (slow but correct)
        float* mP = (float*)d_ws;
        float* sP = mP + plane6;
        float* pP = sP + plane6;
        scan_kernel<1, 6><<<BB * CHUNKS, 256, 0, stream>>>(data, targets, W, nullptr, mP, sP, pP);
        combine_kernel<32><<<(BB * NN) / 4, 256, 0, stream>>>(mP, sP, pP, out);
    }
}